// Round 1
// baseline (2201.244 us; speedup 1.0000x reference)
//
#include <hip/hip_runtime.h>

// DMPNN encoder, MI355X bf16-MFMA implementation.
// Pipeline:
//   cvt_w x3              : W_i/W_h/W_o f32 -> padded packed-bf16 in ws
//   memset tmpA
//   k_init                : h0 = relu([atom[src], bond] @ Wi^T), scatter-add -> tmpA
//   memset tmpB
//   k_msg (writeH=1)      : h1 = relu((tmpA[src] - h0[rev]) @ Wh^T) in-place, scatter -> tmpB
//   memset tmpA
//   k_msg (writeH=0)      : h2 = relu((tmpB[src] - h1[rev]) @ Wh^T), scatter -> tmpA (h2 not stored)
//   k_out                 : out = relu([atom, tmpA] @ Wo^T)  (f32)
//
// MFMA 16x16x32 bf16 verified layouts (learn_hip m89/m91):
//   A frag: lane l holds A[m=l&15][k=(l>>4)*8 + j], j=0..7  (one ds_read_b128)
//   B frag: lane l holds B[k=(l>>4)*8 + j][n=l&15]  == W[n][k] k-contiguous
//   D frag: reg r holds D[row=(l>>4)*4+r][col=l&15]

typedef unsigned int u32;
typedef unsigned short u16;

using bf16x8 = __attribute__((ext_vector_type(8))) __bf16;
using f32x4  = __attribute__((ext_vector_type(4))) float;

#define NN   50000
#define NP   400000
#define NE   800000
#define AF   133
#define BFD  14
#define HID  128

// packed-uint row strides (2 bf16 per uint). Chosen == 4 mod 32 words so the
// 16 b128-fragment lanes spread across all 8 bank-groups (conflict-free).
#define KPU1 100   // k_init: 200 bf16 cols (147 data), 6 k-chunks of 32
#define KPU2 68    // k_msg : 136 bf16 cols (128 data), 4 k-chunks
#define KPU3 148   // k_out : 296 bf16 cols (261 data), 9 k-chunks

__device__ __forceinline__ u16 f2bf(float f) {
    union { float f; u32 u; } x; x.f = f;
    u32 r = x.u + 0x7fffu + ((x.u >> 16) & 1u);   // RNE
    return (u16)(r >> 16);
}
__device__ __forceinline__ float bf2f(u16 b) {
    union { u32 u; float f; } x; x.u = ((u32)b) << 16;
    return x.f;
}
__device__ __forceinline__ u32 pack2(float a, float b) {
    return (u32)f2bf(a) | ((u32)f2bf(b) << 16);
}

// ---- weight convert: W[128][K] f32 -> packed bf16 [128][KpU], zero-padded ----
__global__ void cvt_w(const float* __restrict__ W, u32* __restrict__ out, int K, int KpU) {
    int total = 128 * KpU;
    for (int i = blockIdx.x * blockDim.x + threadIdx.x; i < total; i += gridDim.x * blockDim.x) {
        int n = i / KpU;
        int cu = i - n * KpU;
        int k = cu * 2;
        float f0 = (k < K) ? W[n * K + k] : 0.f;
        float f1 = (k + 1 < K) ? W[n * K + k + 1] : 0.f;
        out[i] = pack2(f0, f1);
    }
}

// ---- k_init: 128-edge tiles, 4 waves, wave tile 64x64 ----
__global__ __launch_bounds__(256, 3)
void k_init(const float* __restrict__ atom, const float* __restrict__ bond,
            const int* __restrict__ src, const int* __restrict__ dst,
            const u32* __restrict__ Wp, u16* __restrict__ hout, float* __restrict__ tmp)
{
    __shared__ u32 As[128 * KPU1];   // 51.2 KB -> 3 blocks/CU
    const int tid = threadIdx.x;
    const int lane = tid & 63;
    const int wv = tid >> 6;
    const int ln = lane & 15;
    const int q  = lane >> 4;
    const int rowBase = 64 * (wv >> 1);
    const int colBase = 64 * (wv & 1);
    const int ntiles = NE / 128;

    for (int tile = blockIdx.x; tile < ntiles; tile += gridDim.x) {
        const int e0 = tile * 128;
        // stage A: row e -> [atom[src[e]](133) | bond[e](14) | 0...]
        for (int i = tid; i < 128 * KPU1; i += 256) {
            int row = i / KPU1;
            int cu = i - row * KPU1;
            int k = cu * 2;
            int e = e0 + row;
            u32 v;
            if (k < 132) {
                const float* ar = atom + src[e] * AF;
                v = pack2(ar[k], ar[k + 1]);
            } else if (k == 132) {
                v = pack2(atom[src[e] * AF + 132], bond[e * BFD]);
            } else if (k < 146) {
                const float* br = bond + e * BFD;
                v = pack2(br[k - 133], br[k - 132]);
            } else if (k == 146) {
                v = pack2(bond[e * BFD + 13], 0.f);
            } else {
                v = 0u;
            }
            As[i] = v;
        }
        __syncthreads();

        f32x4 acc[4][4] = {};
        #pragma unroll
        for (int kc = 0; kc < 6; ++kc) {
            const int kHalf = kc * 16 + q * 4;
            bf16x8 a[4], b[4];
            #pragma unroll
            for (int i = 0; i < 4; ++i)
                a[i] = *(const bf16x8*)(&As[(rowBase + 16 * i + ln) * KPU1 + kHalf]);
            #pragma unroll
            for (int j = 0; j < 4; ++j)
                b[j] = *(const bf16x8*)(Wp + (colBase + 16 * j + ln) * KPU1 + kHalf);
            #pragma unroll
            for (int i = 0; i < 4; ++i)
                #pragma unroll
                for (int j = 0; j < 4; ++j)
                    acc[i][j] = __builtin_amdgcn_mfma_f32_16x16x32_bf16(a[i], b[j], acc[i][j], 0, 0, 0);
        }
        __syncthreads();

        // epilogue: relu, store h (bf16), scatter-add to tmp[dst]
        #pragma unroll
        for (int i = 0; i < 4; ++i) {
            #pragma unroll
            for (int r = 0; r < 4; ++r) {
                int e = e0 + rowBase + 16 * i + q * 4 + r;
                int d = dst[e];
                #pragma unroll
                for (int j = 0; j < 4; ++j) {
                    float v = acc[i][j][r];
                    v = v > 0.f ? v : 0.f;
                    int c = colBase + 16 * j + ln;
                    hout[e * HID + c] = f2bf(v);
                    atomicAdd(&tmp[d * HID + c], v);
                }
            }
        }
    }
}

// ---- k_msg: 64-pair tiles (=128 edges: rows 0..63 fwd p0+r, 64..127 bwd P+p0+r) ----
// In-place h update is safe: rev pairs (i, i+P) are tile-closed.
__global__ __launch_bounds__(256, 3)
void k_msg(const int* __restrict__ src, const int* __restrict__ dst, const int* __restrict__ rev,
           const u32* __restrict__ Wp, const float* __restrict__ tmpIn,
           u16* __restrict__ h, float* __restrict__ tmpOut, const int writeH)
{
    __shared__ u32 As[128 * KPU2];   // 34.8 KB
    const int tid = threadIdx.x;
    const int lane = tid & 63;
    const int wv = tid >> 6;
    const int ln = lane & 15;
    const int q  = lane >> 4;
    const int rowBase = 64 * (wv >> 1);
    const int colBase = 64 * (wv & 1);
    const int ntiles = NP / 64;

    for (int tile = blockIdx.x; tile < ntiles; tile += gridDim.x) {
        const int p0 = tile * 64;
        // stage A: msg[e] = tmpIn[src[e]] - h[rev[e]]
        for (int i = tid; i < 128 * KPU2; i += 256) {
            int row = i / KPU2;
            int cu = i - row * KPU2;
            u32 v = 0u;
            if (cu < 64) {
                int e = (row < 64) ? (p0 + row) : (NP + p0 + (row - 64));
                int s = src[e];
                int re = rev[e];
                int c = cu * 2;
                float2 t = *(const float2*)(tmpIn + s * HID + c);
                u32 hh = *(const u32*)(h + re * HID + c);
                v = pack2(t.x - bf2f((u16)hh), t.y - bf2f((u16)(hh >> 16)));
            }
            As[i] = v;
        }
        __syncthreads();

        f32x4 acc[4][4] = {};
        #pragma unroll
        for (int kc = 0; kc < 4; ++kc) {
            const int kHalf = kc * 16 + q * 4;
            bf16x8 a[4], b[4];
            #pragma unroll
            for (int i = 0; i < 4; ++i)
                a[i] = *(const bf16x8*)(&As[(rowBase + 16 * i + ln) * KPU2 + kHalf]);
            #pragma unroll
            for (int j = 0; j < 4; ++j)
                b[j] = *(const bf16x8*)(Wp + (colBase + 16 * j + ln) * KPU2 + kHalf);
            #pragma unroll
            for (int i = 0; i < 4; ++i)
                #pragma unroll
                for (int j = 0; j < 4; ++j)
                    acc[i][j] = __builtin_amdgcn_mfma_f32_16x16x32_bf16(a[i], b[j], acc[i][j], 0, 0, 0);
        }
        __syncthreads();

        #pragma unroll
        for (int i = 0; i < 4; ++i) {
            #pragma unroll
            for (int r = 0; r < 4; ++r) {
                int rloc = rowBase + 16 * i + q * 4 + r;
                int e = (rloc < 64) ? (p0 + rloc) : (NP + p0 + (rloc - 64));
                int d = dst[e];
                #pragma unroll
                for (int j = 0; j < 4; ++j) {
                    float v = acc[i][j][r];
                    v = v > 0.f ? v : 0.f;
                    int c = colBase + 16 * j + ln;
                    if (writeH) h[e * HID + c] = f2bf(v);
                    atomicAdd(&tmpOut[d * HID + c], v);
                }
            }
        }
    }
}

// ---- k_out: 64-node tiles, wave tile 32x64 ----
__global__ __launch_bounds__(256, 3)
void k_out(const float* __restrict__ atom, const u32* __restrict__ Wp,
           const float* __restrict__ tmpIn, float* __restrict__ out)
{
    __shared__ u32 As[64 * KPU3];    // 37.9 KB
    const int tid = threadIdx.x;
    const int lane = tid & 63;
    const int wv = tid >> 6;
    const int ln = lane & 15;
    const int q  = lane >> 4;
    const int rowBase = 32 * (wv >> 1);
    const int colBase = 64 * (wv & 1);
    const int ntiles = (NN + 63) / 64;

    for (int tile = blockIdx.x; tile < ntiles; tile += gridDim.x) {
        const int n0 = tile * 64;
        for (int i = tid; i < 64 * KPU3; i += 256) {
            int row = i / KPU3;
            int cu = i - row * KPU3;
            int n = n0 + row;
            u32 v = 0u;
            if (n < NN) {
                int k = cu * 2;
                float f0 = (k < AF) ? atom[n * AF + k]
                         : (k < AF + HID ? tmpIn[n * HID + (k - AF)] : 0.f);
                int k1 = k + 1;
                float f1 = (k1 < AF) ? atom[n * AF + k1]
                         : (k1 < AF + HID ? tmpIn[n * HID + (k1 - AF)] : 0.f);
                v = pack2(f0, f1);
            }
            As[i] = v;
        }
        __syncthreads();

        f32x4 acc[2][4] = {};
        #pragma unroll
        for (int kc = 0; kc < 9; ++kc) {
            const int kHalf = kc * 16 + q * 4;
            bf16x8 a[2], b[4];
            #pragma unroll
            for (int i = 0; i < 2; ++i)
                a[i] = *(const bf16x8*)(&As[(rowBase + 16 * i + ln) * KPU3 + kHalf]);
            #pragma unroll
            for (int j = 0; j < 4; ++j)
                b[j] = *(const bf16x8*)(Wp + (colBase + 16 * j + ln) * KPU3 + kHalf);
            #pragma unroll
            for (int i = 0; i < 2; ++i)
                #pragma unroll
                for (int j = 0; j < 4; ++j)
                    acc[i][j] = __builtin_amdgcn_mfma_f32_16x16x32_bf16(a[i], b[j], acc[i][j], 0, 0, 0);
        }
        __syncthreads();

        #pragma unroll
        for (int i = 0; i < 2; ++i) {
            #pragma unroll
            for (int r = 0; r < 4; ++r) {
                int n = n0 + rowBase + 16 * i + q * 4 + r;
                if (n < NN) {
                    #pragma unroll
                    for (int j = 0; j < 4; ++j) {
                        float v = acc[i][j][r];
                        v = v > 0.f ? v : 0.f;
                        out[n * HID + colBase + 16 * j + ln] = v;
                    }
                }
            }
        }
    }
}

extern "C" void kernel_launch(void* const* d_in, const int* in_sizes, int n_in,
                              void* d_out, int out_size, void* d_ws, size_t ws_size,
                              hipStream_t stream) {
    const float* atom = (const float*)d_in[0];   // [50000][133]
    const float* bond = (const float*)d_in[1];   // [800000][14]
    const float* Wi   = (const float*)d_in[2];   // [128][147]
    const float* Wh   = (const float*)d_in[3];   // [128][128]
    const float* Wo   = (const float*)d_in[4];   // [128][261]
    const int*   src  = (const int*)d_in[5];     // [800000]
    const int*   dst  = (const int*)d_in[6];
    const int*   rev  = (const int*)d_in[7];
    float* out = (float*)d_out;

    char* ws = (char*)d_ws;
    u16*  hbuf = (u16*)ws;                         // 204,800,000 B  (bf16 h[E][128])
    size_t off = (size_t)NE * HID * 2;
    float* tmpA = (float*)(ws + off); off += (size_t)NN * HID * 4;   // 25.6 MB
    float* tmpB = (float*)(ws + off); off += (size_t)NN * HID * 4;   // 25.6 MB
    u32* wWi = (u32*)(ws + off); off += 128 * KPU1 * 4;
    u32* wWh = (u32*)(ws + off); off += 128 * KPU2 * 4;
    u32* wWo = (u32*)(ws + off); off += 128 * KPU3 * 4;
    // total ~256.2 MB of ws

    cvt_w<<<50, 256, 0, stream>>>(Wi, wWi, AF + BFD, KPU1);
    cvt_w<<<34, 256, 0, stream>>>(Wh, wWh, HID, KPU2);
    cvt_w<<<74, 256, 0, stream>>>(Wo, wWo, AF + HID, KPU3);

    hipMemsetAsync(tmpA, 0, (size_t)NN * HID * 4, stream);
    k_init<<<768, 256, 0, stream>>>(atom, bond, src, dst, wWi, hbuf, tmpA);

    hipMemsetAsync(tmpB, 0, (size_t)NN * HID * 4, stream);
    k_msg<<<1024, 256, 0, stream>>>(src, dst, rev, wWh, tmpA, hbuf, tmpB, 1);

    hipMemsetAsync(tmpA, 0, (size_t)NN * HID * 4, stream);
    k_msg<<<1024, 256, 0, stream>>>(src, dst, rev, wWh, tmpB, hbuf, tmpA, 0);

    k_out<<<782, 256, 0, stream>>>(atom, wWo, tmpA, out);
}

// Round 2
// 1148.919 us; speedup vs baseline: 1.9159x; 1.9159x over previous
//
#include <hip/hip_runtime.h>

// DMPNN encoder, MI355X bf16-MFMA, round 2: atomic-free CSR segment-sum.
//
// Pipeline (all per call, stream-ordered):
//   cvt_atom         : atom f32[50000][133] -> packed bf16 atomBf[50000][68 u32] (3 zero pad cols)
//   cvt_w x3         : Wi/Wh/Wo -> packed bf16, layout-permuted to match A tiles
//   memset cnt; hist : cnt[d] = in-degree            (int atomics)
//   scan1/2/3        : exclusive scan -> rowptr, cursor
//   scatter          : eidx grouped by dst           (int atomics)
//   k_init           : h = relu([atomBf[src],bond] @ WiP) -> hbuf (bf16)   [no atomics]
//   segsum           : tmp[n] = sum_{e: dst=n} h[e]  (CSR gather, bf16 out)
//   k_msg            : h = relu((tmp[src]-h[rev]) @ WhP) in-place (tiles pair-closed)
//   segsum, k_msg, segsum
//   k_out            : out = relu([atomBf, tmp] @ WoP)  (f32)
//
// MFMA 16x16x32 bf16 layouts (learn_hip m89/m91):
//   A frag: lane l holds A[m=l&15][k=(l>>4)*8+j]   (one 16B read)
//   B frag: lane l holds B[k=(l>>4)*8+j][n=l&15] == W[n][k] k-contiguous
//   D frag: reg r holds D[row=(l>>4)*4+r][col=l&15]
// LDS row strides (u32): ≡4 mod 8 so b128 frag reads spread all 8 bank groups.

typedef unsigned int u32;
typedef unsigned short u16;
using bf16x8 = __attribute__((ext_vector_type(8))) __bf16;
using f32x4  = __attribute__((ext_vector_type(4))) float;

#define NN 50000
#define NP 400000
#define NE 800000
#define AF 133
#define HID 128
#define ATU 68      // atomBf row stride in u32 (136 bf16 = 133 data + 3 zero)
#define KPU1 84     // k_init LDS stride; 80 data u32 = 160 cols = 5 chunks
#define KC1 5
#define KPU2 68     // k_msg stride; 64 data u32 = 128 cols = 4 chunks
#define KC2 4
#define KPU3 148    // k_out stride; 144 data u32 = 288 cols = 9 chunks
#define KC3 9
#define NCH 196     // scan chunks of 256 covering 50000

__device__ __forceinline__ u16 f2bf(float f) {
    union { float f; u32 u; } x; x.f = f;
    u32 r = x.u + 0x7fffu + ((x.u >> 16) & 1u);   // RNE
    return (u16)(r >> 16);
}
__device__ __forceinline__ float bf2f(u16 b) {
    union { u32 u; float f; } x; x.u = ((u32)b) << 16;
    return x.f;
}
__device__ __forceinline__ u32 pack2(float a, float b) {
    return (u32)f2bf(a) | ((u32)f2bf(b) << 16);
}
// packed bf16 pair subtract: (t - h) per half, repacked
__device__ __forceinline__ u32 sub2(u32 t, u32 h) {
    float a0 = bf2f((u16)t)        - bf2f((u16)h);
    float a1 = bf2f((u16)(t >> 16)) - bf2f((u16)(h >> 16));
    return pack2(a0, a1);
}

// ---------------- precompute kernels ----------------

__global__ void cvt_atom(const float* __restrict__ atom, u32* __restrict__ out) {
    int total = NN * ATU;
    for (int i = blockIdx.x * blockDim.x + threadIdx.x; i < total; i += gridDim.x * blockDim.x) {
        int n = i / ATU;
        int cu = i - n * ATU;
        int k = 2 * cu;
        float f0 = (k < AF) ? atom[n * AF + k] : 0.f;
        float f1 = (k + 1 < AF) ? atom[n * AF + k + 1] : 0.f;
        out[i] = pack2(f0, f1);
    }
}

__device__ __forceinline__ float wcol(const float* W, int n, int Kw, int len1, int off2, int len2, int k) {
    if (k < len1) return W[n * Kw + k];
    int j = k - off2;
    if (j >= 0 && j < len2) return W[n * Kw + len1 + j];
    return 0.f;
}
__global__ void cvt_w(const float* __restrict__ W, u32* __restrict__ out,
                      int Kw, int KpU, int len1, int off2, int len2) {
    int total = 128 * KpU;
    for (int i = blockIdx.x * blockDim.x + threadIdx.x; i < total; i += gridDim.x * blockDim.x) {
        int n = i / KpU;
        int cu = i - n * KpU;
        int k = 2 * cu;
        out[i] = pack2(wcol(W, n, Kw, len1, off2, len2, k),
                       wcol(W, n, Kw, len1, off2, len2, k + 1));
    }
}

// ---------------- CSR build ----------------

__global__ void hist(const int* __restrict__ dst, int* __restrict__ cnt) {
    for (int e = blockIdx.x * blockDim.x + threadIdx.x; e < NE; e += gridDim.x * blockDim.x)
        atomicAdd(&cnt[dst[e]], 1);
}

__global__ void scan1(const int* __restrict__ cnt, int* __restrict__ lexc, int* __restrict__ chunkSum) {
    __shared__ int s[256];
    int t = threadIdx.x, idx = blockIdx.x * 256 + t;
    int v = (idx < NN) ? cnt[idx] : 0;
    s[t] = v; __syncthreads();
    for (int off = 1; off < 256; off <<= 1) {
        int x = (t >= off) ? s[t - off] : 0;
        __syncthreads();
        s[t] += x;
        __syncthreads();
    }
    if (idx < NN) lexc[idx] = s[t] - v;
    if (t == 255) chunkSum[blockIdx.x] = s[255];
}

__global__ void scan2(const int* __restrict__ chunkSum, int* __restrict__ chunkOff) {
    __shared__ int s[256];
    int t = threadIdx.x;
    int v = (t < NCH) ? chunkSum[t] : 0;
    s[t] = v; __syncthreads();
    for (int off = 1; off < 256; off <<= 1) {
        int x = (t >= off) ? s[t - off] : 0;
        __syncthreads();
        s[t] += x;
        __syncthreads();
    }
    if (t < NCH) chunkOff[t] = s[t] - v;
}

__global__ void scan3(const int* __restrict__ lexc, const int* __restrict__ chunkOff,
                      int* __restrict__ rowptr, int* __restrict__ cursor) {
    int idx = blockIdx.x * 256 + threadIdx.x;
    if (idx < NN) {
        int v = lexc[idx] + chunkOff[blockIdx.x];
        rowptr[idx] = v;
        cursor[idx] = v;
    }
    if (idx == 0) rowptr[NN] = NE;
}

__global__ void scatter(const int* __restrict__ dst, int* __restrict__ cursor, int* __restrict__ eidx) {
    for (int e = blockIdx.x * blockDim.x + threadIdx.x; e < NE; e += gridDim.x * blockDim.x) {
        int pos = atomicAdd(&cursor[dst[e]], 1);
        eidx[pos] = e;
    }
}

// ---------------- segment sum (CSR gather) ----------------
// one wave per node; lane l owns cols 2l, 2l+1; h rows are 64 u32 (256B) coalesced.
__global__ __launch_bounds__(256)
void segsum(const int* __restrict__ rowptr, const int* __restrict__ eidx,
            const u32* __restrict__ h, u32* __restrict__ tmp) {
    const int lane = threadIdx.x & 63;
    const int wv = threadIdx.x >> 6;
    for (int n = blockIdx.x * 4 + wv; n < NN; n += gridDim.x * 4) {
        int beg = rowptr[n], end = rowptr[n + 1];
        float a0 = 0.f, a1 = 0.f;
        int i = beg;
        for (; i + 2 <= end; i += 2) {
            int e0 = eidx[i], e1 = eidx[i + 1];
            u32 h0 = h[(size_t)e0 * 64 + lane];
            u32 h1 = h[(size_t)e1 * 64 + lane];
            a0 += bf2f((u16)h0) + bf2f((u16)h1);
            a1 += bf2f((u16)(h0 >> 16)) + bf2f((u16)(h1 >> 16));
        }
        if (i < end) {
            u32 h0 = h[(size_t)eidx[i] * 64 + lane];
            a0 += bf2f((u16)h0);
            a1 += bf2f((u16)(h0 >> 16));
        }
        tmp[n * 64 + lane] = pack2(a0, a1);
    }
}

// ---------------- k_init: 128-edge tiles, 4 waves (64x64 each) ----------------
__global__ __launch_bounds__(256, 3)
void k_init(const u32* __restrict__ atomBf, const float* __restrict__ bond,
            const int* __restrict__ src, const u32* __restrict__ Wp,
            u16* __restrict__ hout)
{
    __shared__ u32 As[128 * KPU1];   // 43008 B -> 3 blocks/CU
    const int tid = threadIdx.x;
    const int lane = tid & 63;
    const int wv = tid >> 6;
    const int ln = lane & 15;
    const int q  = lane >> 4;
    const int rowBase = 64 * (wv >> 1);
    const int colBase = 64 * (wv & 1);
    const int ntiles = NE / 128;

    const int srow = tid >> 1;       // staging row
    const int half = tid & 1;

    for (int tile = blockIdx.x; tile < ntiles; tile += gridDim.x) {
        const int e0 = tile * 128;
        {
            int e = e0 + srow;
            const u32* ap = atomBf + (size_t)src[e] * ATU;
            u32* dr = As + srow * KPU1;
            if (half == 0) {
                #pragma unroll
                for (int j = 0; j < 10; ++j)
                    *(uint4*)(dr + 4 * j) = *(const uint4*)(ap + 4 * j);
            } else {
                #pragma unroll
                for (int j = 10; j < 17; ++j)
                    *(uint4*)(dr + 4 * j) = *(const uint4*)(ap + 4 * j);
                const float* bp = bond + (size_t)e * 14;
                u32 b0 = pack2(bp[0], bp[1]),  b1 = pack2(bp[2], bp[3]);
                u32 b2 = pack2(bp[4], bp[5]),  b3 = pack2(bp[6], bp[7]);
                u32 b4 = pack2(bp[8], bp[9]),  b5 = pack2(bp[10], bp[11]);
                u32 b6 = pack2(bp[12], bp[13]);
                *(uint4*)(dr + 68) = make_uint4(b0, b1, b2, b3);
                *(uint4*)(dr + 72) = make_uint4(b4, b5, b6, 0u);
                *(uint4*)(dr + 76) = make_uint4(0u, 0u, 0u, 0u);
            }
        }
        __syncthreads();

        f32x4 acc[4][4] = {};
        #pragma unroll
        for (int kc = 0; kc < KC1; ++kc) {
            const int kHalf = kc * 16 + q * 4;
            bf16x8 a[4], b[4];
            #pragma unroll
            for (int i = 0; i < 4; ++i)
                a[i] = *(const bf16x8*)(&As[(rowBase + 16 * i + ln) * KPU1 + kHalf]);
            #pragma unroll
            for (int j = 0; j < 4; ++j)
                b[j] = *(const bf16x8*)(Wp + (colBase + 16 * j + ln) * KPU1 + kHalf);
            #pragma unroll
            for (int i = 0; i < 4; ++i)
                #pragma unroll
                for (int j = 0; j < 4; ++j)
                    acc[i][j] = __builtin_amdgcn_mfma_f32_16x16x32_bf16(a[i], b[j], acc[i][j], 0, 0, 0);
        }
        __syncthreads();

        #pragma unroll
        for (int i = 0; i < 4; ++i) {
            #pragma unroll
            for (int r = 0; r < 4; ++r) {
                int e = e0 + rowBase + 16 * i + q * 4 + r;
                #pragma unroll
                for (int j = 0; j < 4; ++j) {
                    float v = acc[i][j][r];
                    v = v > 0.f ? v : 0.f;
                    hout[(size_t)e * HID + colBase + 16 * j + ln] = f2bf(v);
                }
            }
        }
    }
}

// ---------------- k_msg: 64-pair tiles (128 edges, pair-closed rev) ----------------
__global__ __launch_bounds__(256, 4)
void k_msg(const int* __restrict__ src, const int* __restrict__ rev,
           const u32* __restrict__ Wp, const u32* __restrict__ tmp,
           u16* __restrict__ h)
{
    __shared__ u32 As[128 * KPU2];   // 34816 B -> 4 blocks/CU
    const int tid = threadIdx.x;
    const int lane = tid & 63;
    const int wv = tid >> 6;
    const int ln = lane & 15;
    const int q  = lane >> 4;
    const int rowBase = 64 * (wv >> 1);
    const int colBase = 64 * (wv & 1);
    const int ntiles = NP / 64;

    const int srow = tid >> 1;
    const int half = tid & 1;
    const u32* hu = (const u32*)h;

    for (int tile = blockIdx.x; tile < ntiles; tile += gridDim.x) {
        const int p0 = tile * 64;
        {
            int e = (srow < 64) ? (p0 + srow) : (NP + p0 + (srow - 64));
            const u32* tp = tmp + (size_t)src[e] * 64 + half * 32;
            const u32* hp = hu + (size_t)rev[e] * 64 + half * 32;
            u32* dr = As + srow * KPU2 + half * 32;
            #pragma unroll
            for (int j = 0; j < 8; ++j) {
                uint4 tv = ((const uint4*)tp)[j];
                uint4 hv = ((const uint4*)hp)[j];
                uint4 o;
                o.x = sub2(tv.x, hv.x); o.y = sub2(tv.y, hv.y);
                o.z = sub2(tv.z, hv.z); o.w = sub2(tv.w, hv.w);
                ((uint4*)dr)[j] = o;
            }
        }
        __syncthreads();

        f32x4 acc[4][4] = {};
        #pragma unroll
        for (int kc = 0; kc < KC2; ++kc) {
            const int kHalf = kc * 16 + q * 4;
            bf16x8 a[4], b[4];
            #pragma unroll
            for (int i = 0; i < 4; ++i)
                a[i] = *(const bf16x8*)(&As[(rowBase + 16 * i + ln) * KPU2 + kHalf]);
            #pragma unroll
            for (int j = 0; j < 4; ++j)
                b[j] = *(const bf16x8*)(Wp + (colBase + 16 * j + ln) * KPU2 + kHalf);
            #pragma unroll
            for (int i = 0; i < 4; ++i)
                #pragma unroll
                for (int j = 0; j < 4; ++j)
                    acc[i][j] = __builtin_amdgcn_mfma_f32_16x16x32_bf16(a[i], b[j], acc[i][j], 0, 0, 0);
        }
        __syncthreads();

        #pragma unroll
        for (int i = 0; i < 4; ++i) {
            #pragma unroll
            for (int r = 0; r < 4; ++r) {
                int rloc = rowBase + 16 * i + q * 4 + r;
                int e = (rloc < 64) ? (p0 + rloc) : (NP + p0 + (rloc - 64));
                #pragma unroll
                for (int j = 0; j < 4; ++j) {
                    float v = acc[i][j][r];
                    v = v > 0.f ? v : 0.f;
                    h[(size_t)e * HID + colBase + 16 * j + ln] = f2bf(v);
                }
            }
        }
    }
}

// ---------------- k_out: 64-node tiles, 4 waves (32x64 each) ----------------
__global__ __launch_bounds__(256, 4)
void k_out(const u32* __restrict__ atomBf, const u32* __restrict__ Wp,
           const u32* __restrict__ tmp, float* __restrict__ out)
{
    __shared__ u32 As[64 * KPU3];   // 37888 B -> 4 blocks/CU
    const int tid = threadIdx.x;
    const int lane = tid & 63;
    const int wv = tid >> 6;
    const int ln = lane & 15;
    const int q  = lane >> 4;
    const int rowBase = 32 * (wv >> 1);
    const int colBase = 64 * (wv & 1);
    const int ntiles = (NN + 63) / 64;

    const int srow = tid >> 2;
    const int qt = tid & 3;
    const uint4 z4 = make_uint4(0u, 0u, 0u, 0u);

    for (int tile = blockIdx.x; tile < ntiles; tile += gridDim.x) {
        const int n0 = tile * 64;
        {
            int n = n0 + srow;
            bool ok = n < NN;
            const u32* ap = atomBf + (size_t)n * ATU;
            const u32* tp = tmp + (size_t)n * 64;
            u32* dr = As + srow * KPU3;
            if (qt == 0) {
                #pragma unroll
                for (int j = 0; j < 9; ++j)
                    *(uint4*)(dr + 4 * j) = ok ? *(const uint4*)(ap + 4 * j) : z4;
            } else if (qt == 1) {
                #pragma unroll
                for (int j = 9; j < 17; ++j)
                    *(uint4*)(dr + 4 * j) = ok ? *(const uint4*)(ap + 4 * j) : z4;
            } else if (qt == 2) {
                #pragma unroll
                for (int j = 0; j < 8; ++j)
                    *(uint4*)(dr + 68 + 4 * j) = ok ? *(const uint4*)(tp + 4 * j) : z4;
                *(uint4*)(dr + 132) = z4;
            } else {
                #pragma unroll
                for (int j = 8; j < 16; ++j)
                    *(uint4*)(dr + 68 + 4 * j) = ok ? *(const uint4*)(tp + 4 * j) : z4;
                *(uint4*)(dr + 136) = z4;
                *(uint4*)(dr + 140) = z4;
            }
        }
        __syncthreads();

        f32x4 acc[2][4] = {};
        #pragma unroll
        for (int kc = 0; kc < KC3; ++kc) {
            const int kHalf = kc * 16 + q * 4;
            bf16x8 a[2], b[4];
            #pragma unroll
            for (int i = 0; i < 2; ++i)
                a[i] = *(const bf16x8*)(&As[(rowBase + 16 * i + ln) * KPU3 + kHalf]);
            #pragma unroll
            for (int j = 0; j < 4; ++j)
                b[j] = *(const bf16x8*)(Wp + (colBase + 16 * j + ln) * KPU3 + kHalf);
            #pragma unroll
            for (int i = 0; i < 2; ++i)
                #pragma unroll
                for (int j = 0; j < 4; ++j)
                    acc[i][j] = __builtin_amdgcn_mfma_f32_16x16x32_bf16(a[i], b[j], acc[i][j], 0, 0, 0);
        }
        __syncthreads();

        #pragma unroll
        for (int i = 0; i < 2; ++i) {
            #pragma unroll
            for (int r = 0; r < 4; ++r) {
                int n = n0 + rowBase + 16 * i + q * 4 + r;
                if (n < NN) {
                    #pragma unroll
                    for (int j = 0; j < 4; ++j) {
                        float v = acc[i][j][r];
                        out[(size_t)n * HID + colBase + 16 * j + ln] = v > 0.f ? v : 0.f;
                    }
                }
            }
        }
    }
}

// ---------------- launch ----------------

extern "C" void kernel_launch(void* const* d_in, const int* in_sizes, int n_in,
                              void* d_out, int out_size, void* d_ws, size_t ws_size,
                              hipStream_t stream) {
    const float* atom = (const float*)d_in[0];   // [50000][133]
    const float* bond = (const float*)d_in[1];   // [800000][14]
    const float* Wi   = (const float*)d_in[2];   // [128][147]
    const float* Wh   = (const float*)d_in[3];   // [128][128]
    const float* Wo   = (const float*)d_in[4];   // [128][261]
    const int*   src  = (const int*)d_in[5];
    const int*   dst  = (const int*)d_in[6];
    const int*   rev  = (const int*)d_in[7];
    float* out = (float*)d_out;

    char* ws = (char*)d_ws;
    size_t off = 0;
    auto take = [&](size_t bytes) { char* p = ws + off; off = (off + bytes + 255) & ~(size_t)255; return p; };
    u32* hbuf   = (u32*)take((size_t)NE * 64 * 4);     // 204.8 MB  bf16 h[E][128]
    u32* tmp    = (u32*)take((size_t)NN * 64 * 4);     // 12.8 MB   bf16 tmp[N][128]
    u32* atomBf = (u32*)take((size_t)NN * ATU * 4);    // 13.6 MB
    int* eidx   = (int*)take((size_t)NE * 4);          // 3.2 MB
    int* cnt    = (int*)take((size_t)NN * 4);
    int* lexc   = (int*)take((size_t)NN * 4);
    int* rowptr = (int*)take((size_t)(NN + 1) * 4);
    int* cursor = (int*)take((size_t)NN * 4);
    int* chunkSum = (int*)take(256 * 4);
    int* chunkOff = (int*)take(256 * 4);
    u32* WiP = (u32*)take(128 * KPU1 * 4);
    u32* WhP = (u32*)take(128 * KPU2 * 4);
    u32* WoP = (u32*)take(128 * KPU3 * 4);
    // total ~235.6 MB

    cvt_atom<<<2048, 256, 0, stream>>>(atom, atomBf);
    cvt_w<<<48, 256, 0, stream>>>(Wi, WiP, 147, KPU1, 133, 136, 14);
    cvt_w<<<48, 256, 0, stream>>>(Wh, WhP, 128, KPU2, 128, 1 << 20, 0);
    cvt_w<<<80, 256, 0, stream>>>(Wo, WoP, 261, KPU3, 133, 136, 128);

    hipMemsetAsync(cnt, 0, (size_t)NN * 4, stream);
    hist<<<1024, 256, 0, stream>>>(dst, cnt);
    scan1<<<NCH, 256, 0, stream>>>(cnt, lexc, chunkSum);
    scan2<<<1, 256, 0, stream>>>(chunkSum, chunkOff);
    scan3<<<NCH, 256, 0, stream>>>(lexc, chunkOff, rowptr, cursor);
    scatter<<<1024, 256, 0, stream>>>(dst, cursor, eidx);

    k_init<<<768, 256, 0, stream>>>(atomBf, bond, src, WiP, (u16*)hbuf);
    segsum<<<1024, 256, 0, stream>>>(rowptr, eidx, hbuf, tmp);
    k_msg<<<1024, 256, 0, stream>>>(src, rev, WhP, tmp, (u16*)hbuf);
    segsum<<<1024, 256, 0, stream>>>(rowptr, eidx, hbuf, tmp);
    k_msg<<<1024, 256, 0, stream>>>(src, rev, WhP, tmp, (u16*)hbuf);
    segsum<<<1024, 256, 0, stream>>>(rowptr, eidx, hbuf, tmp);
    k_out<<<782, 256, 0, stream>>>(atomBf, WoP, tmp, out);
}

// Round 3
// 894.853 us; speedup vs baseline: 2.4599x; 1.2839x over previous
//
#include <hip/hip_runtime.h>

// DMPNN encoder, MI355X bf16-MFMA, round 3:
//   - k_init processes edges in src-sorted order (f = rev[eidx]) so the atom
//     gather becomes a streaming re-read (L1/L2 hot); h rows written scattered
//     (256-B aligned => full-line writes).
//   - Weight output channels permuted so each lane's j=0/1 (j=2/3) fragments
//     hold adjacent channels -> epilogue stores packed u32 bf16x2 (64B groups).
//   - segsum v2: 4-rows-per-chunk lane split, fully coalesced wave loads,
//     shfl_xor combine. No serial per-edge latency chain.
//
// MFMA 16x16x32 bf16 layouts (learn_hip m89/m91):
//   A frag: lane l holds A[m=l&15][k=(l>>4)*8+j]
//   B frag: lane l holds B[k=(l>>4)*8+j][n=l&15] == W[n][k] k-contiguous
//   D frag: reg r holds D[row=(l>>4)*4+r][col=l&15]
// Channel permutation: Wp row p holds weights of actual channel
//   c(p) = (p&64) + 2*(p&15) + ((p>>4)&1) + 32*((p>>5)&1)

typedef unsigned int u32;
typedef unsigned short u16;
using bf16x8 = __attribute__((ext_vector_type(8))) __bf16;
using f32x4  = __attribute__((ext_vector_type(4))) float;

#define NN 50000
#define NP 400000
#define NE 800000
#define AF 133
#define HID 128
#define ATU 68      // atomBf row stride in u32 (136 bf16 = 133 data + 3 zero)
#define KPU1 84     // k_init LDS stride; 80 data u32 = 160 cols = 5 chunks
#define KC1 5
#define KPU2 68     // k_msg stride; 64 data u32 = 128 cols = 4 chunks
#define KC2 4
#define KPU3 148    // k_out stride; 144 data u32 = 288 cols = 9 chunks
#define KC3 9
#define NCH 196     // scan chunks of 256 covering 50000

__device__ __forceinline__ u16 f2bf(float f) {
    union { float f; u32 u; } x; x.f = f;
    u32 r = x.u + 0x7fffu + ((x.u >> 16) & 1u);   // RNE
    return (u16)(r >> 16);
}
__device__ __forceinline__ float bf2f(u16 b) {
    union { u32 u; float f; } x; x.u = ((u32)b) << 16;
    return x.f;
}
__device__ __forceinline__ float lo16(u32 v) { return bf2f((u16)v); }
__device__ __forceinline__ float hi16(u32 v) { return bf2f((u16)(v >> 16)); }
__device__ __forceinline__ u32 pack2(float a, float b) {
    return (u32)f2bf(a) | ((u32)f2bf(b) << 16);
}
__device__ __forceinline__ u32 sub2(u32 t, u32 h) {
    return pack2(lo16(t) - lo16(h), hi16(t) - hi16(h));
}
__device__ __forceinline__ float relu(float v) { return v > 0.f ? v : 0.f; }

// ---------------- precompute kernels ----------------

__global__ void cvt_atom(const float* __restrict__ atom, u32* __restrict__ out) {
    int total = NN * ATU;
    for (int i = blockIdx.x * blockDim.x + threadIdx.x; i < total; i += gridDim.x * blockDim.x) {
        int n = i / ATU;
        int cu = i - n * ATU;
        int k = 2 * cu;
        float f0 = (k < AF) ? atom[n * AF + k] : 0.f;
        float f1 = (k + 1 < AF) ? atom[n * AF + k + 1] : 0.f;
        out[i] = pack2(f0, f1);
    }
}

__device__ __forceinline__ float wcol(const float* W, int n, int Kw, int len1, int off2, int len2, int k) {
    if (k < len1) return W[n * Kw + k];
    int j = k - off2;
    if (j >= 0 && j < len2) return W[n * Kw + len1 + j];
    return 0.f;
}
// Wp row p <- actual channel c(p) (output-channel permutation for packed stores)
__global__ void cvt_w(const float* __restrict__ W, u32* __restrict__ out,
                      int Kw, int KpU, int len1, int off2, int len2) {
    int total = 128 * KpU;
    for (int i = blockIdx.x * blockDim.x + threadIdx.x; i < total; i += gridDim.x * blockDim.x) {
        int p = i / KpU;
        int cu = i - p * KpU;
        int t = p & 63;
        int c = (p & 64) + 2 * (t & 15) + ((t >> 4) & 1) + 32 * ((t >> 5) & 1);
        int k = 2 * cu;
        out[i] = pack2(wcol(W, c, Kw, len1, off2, len2, k),
                       wcol(W, c, Kw, len1, off2, len2, k + 1));
    }
}

// ---------------- CSR build ----------------

__global__ void hist(const int* __restrict__ dst, int* __restrict__ cnt) {
    for (int e = blockIdx.x * blockDim.x + threadIdx.x; e < NE; e += gridDim.x * blockDim.x)
        atomicAdd(&cnt[dst[e]], 1);
}

__global__ void scan1(const int* __restrict__ cnt, int* __restrict__ lexc, int* __restrict__ chunkSum) {
    __shared__ int s[256];
    int t = threadIdx.x, idx = blockIdx.x * 256 + t;
    int v = (idx < NN) ? cnt[idx] : 0;
    s[t] = v; __syncthreads();
    for (int off = 1; off < 256; off <<= 1) {
        int x = (t >= off) ? s[t - off] : 0;
        __syncthreads();
        s[t] += x;
        __syncthreads();
    }
    if (idx < NN) lexc[idx] = s[t] - v;
    if (t == 255) chunkSum[blockIdx.x] = s[255];
}

__global__ void scan2(const int* __restrict__ chunkSum, int* __restrict__ chunkOff) {
    __shared__ int s[256];
    int t = threadIdx.x;
    int v = (t < NCH) ? chunkSum[t] : 0;
    s[t] = v; __syncthreads();
    for (int off = 1; off < 256; off <<= 1) {
        int x = (t >= off) ? s[t - off] : 0;
        __syncthreads();
        s[t] += x;
        __syncthreads();
    }
    if (t < NCH) chunkOff[t] = s[t] - v;
}

__global__ void scan3(const int* __restrict__ lexc, const int* __restrict__ chunkOff,
                      int* __restrict__ rowptr, int* __restrict__ cursor) {
    int idx = blockIdx.x * 256 + threadIdx.x;
    if (idx < NN) {
        int v = lexc[idx] + chunkOff[blockIdx.x];
        rowptr[idx] = v;
        cursor[idx] = v;
    }
    if (idx == 0) rowptr[NN] = NE;
}

__global__ void scatter(const int* __restrict__ dst, const int* __restrict__ rev,
                        int* __restrict__ cursor, int* __restrict__ eidx,
                        int* __restrict__ fidx, int* __restrict__ sidx) {
    for (int e = blockIdx.x * blockDim.x + threadIdx.x; e < NE; e += gridDim.x * blockDim.x) {
        int d = dst[e];
        int pos = atomicAdd(&cursor[d], 1);
        eidx[pos] = e;        // edges grouped by dst  (segsum order)
        fidx[pos] = rev[e];   // same positions: rev[e] grouped by src[rev[e]]=d
        sidx[pos] = d;        // = src[fidx[pos]], sorted nondecreasing
    }
}

// ---------------- segment sum v2 (CSR gather, chunked-parallel) ----------------
// one wave per node; chunk = 4 rows loaded by the whole wave in one coalesced
// 1KB access: lane l -> row i+(l>>4), uint4 col group (l&15).
__global__ __launch_bounds__(256)
void segsum(const int* __restrict__ rowptr, const int* __restrict__ eidx,
            const u32* __restrict__ h, u32* __restrict__ tmp) {
    const int lane = threadIdx.x & 63;
    const int wv = threadIdx.x >> 6;
    const int rsel = lane >> 4;
    const int cg = lane & 15;
    const int nwaves = gridDim.x * 4;
    for (int n = blockIdx.x * 4 + wv; n < NN; n += nwaves) {
        int beg = rowptr[n], end = rowptr[n + 1];
        float a0 = 0, a1 = 0, a2 = 0, a3 = 0, a4 = 0, a5 = 0, a6 = 0, a7 = 0;
        int i = beg;
        for (; i + 8 <= end; i += 8) {
            int eA = eidx[i + rsel];
            int eB = eidx[i + 4 + rsel];
            uint4 hA = *(const uint4*)(h + (size_t)eA * 64 + 4 * cg);
            uint4 hB = *(const uint4*)(h + (size_t)eB * 64 + 4 * cg);
            a0 += lo16(hA.x) + lo16(hB.x); a1 += hi16(hA.x) + hi16(hB.x);
            a2 += lo16(hA.y) + lo16(hB.y); a3 += hi16(hA.y) + hi16(hB.y);
            a4 += lo16(hA.z) + lo16(hB.z); a5 += hi16(hA.z) + hi16(hB.z);
            a6 += lo16(hA.w) + lo16(hB.w); a7 += hi16(hA.w) + hi16(hB.w);
        }
        for (; i < end; i += 4) {
            if (i + rsel < end) {
                int eA = eidx[i + rsel];
                uint4 hA = *(const uint4*)(h + (size_t)eA * 64 + 4 * cg);
                a0 += lo16(hA.x); a1 += hi16(hA.x);
                a2 += lo16(hA.y); a3 += hi16(hA.y);
                a4 += lo16(hA.z); a5 += hi16(hA.z);
                a6 += lo16(hA.w); a7 += hi16(hA.w);
            }
        }
        a0 += __shfl_xor(a0, 16); a0 += __shfl_xor(a0, 32);
        a1 += __shfl_xor(a1, 16); a1 += __shfl_xor(a1, 32);
        a2 += __shfl_xor(a2, 16); a2 += __shfl_xor(a2, 32);
        a3 += __shfl_xor(a3, 16); a3 += __shfl_xor(a3, 32);
        a4 += __shfl_xor(a4, 16); a4 += __shfl_xor(a4, 32);
        a5 += __shfl_xor(a5, 16); a5 += __shfl_xor(a5, 32);
        a6 += __shfl_xor(a6, 16); a6 += __shfl_xor(a6, 32);
        a7 += __shfl_xor(a7, 16); a7 += __shfl_xor(a7, 32);
        if (rsel == 0) {
            uint4 o;
            o.x = pack2(a0, a1); o.y = pack2(a2, a3);
            o.z = pack2(a4, a5); o.w = pack2(a6, a7);
            *(uint4*)(tmp + (size_t)n * 64 + 4 * cg) = o;
        }
    }
}

// ---------------- k_init: src-sorted 128-edge tiles, 4 waves (64x64) ----------------
__global__ __launch_bounds__(256, 3)
void k_init(const u32* __restrict__ atomBf, const float* __restrict__ bond,
            const int* __restrict__ fidx, const int* __restrict__ sidx,
            const u32* __restrict__ Wp, u32* __restrict__ hout)
{
    __shared__ u32 As[128 * KPU1];   // 43008 B -> 3 blocks/CU
    const int tid = threadIdx.x;
    const int lane = tid & 63;
    const int wv = tid >> 6;
    const int ln = lane & 15;
    const int q  = lane >> 4;
    const int rowBase = 64 * (wv >> 1);
    const int cbU = 32 * (wv & 1);          // packed u32 col base
    const int ntiles = NE / 128;

    const int srow = tid >> 1;
    const int half = tid & 1;

    for (int tile = blockIdx.x; tile < ntiles; tile += gridDim.x) {
        const int e0 = tile * 128;
        {
            int p = e0 + srow;
            const u32* ap = atomBf + (size_t)sidx[p] * ATU;
            u32* dr = As + srow * KPU1;
            if (half == 0) {
                #pragma unroll
                for (int j = 0; j < 10; ++j)
                    *(uint4*)(dr + 4 * j) = *(const uint4*)(ap + 4 * j);
            } else {
                #pragma unroll
                for (int j = 10; j < 17; ++j)
                    *(uint4*)(dr + 4 * j) = *(const uint4*)(ap + 4 * j);
                const float* bp = bond + (size_t)fidx[p] * 14;
                float2 b0 = *(const float2*)(bp + 0);
                float2 b1 = *(const float2*)(bp + 2);
                float2 b2 = *(const float2*)(bp + 4);
                float2 b3 = *(const float2*)(bp + 6);
                float2 b4 = *(const float2*)(bp + 8);
                float2 b5 = *(const float2*)(bp + 10);
                float2 b6 = *(const float2*)(bp + 12);
                *(uint4*)(dr + 68) = make_uint4(pack2(b0.x, b0.y), pack2(b1.x, b1.y),
                                                pack2(b2.x, b2.y), pack2(b3.x, b3.y));
                *(uint4*)(dr + 72) = make_uint4(pack2(b4.x, b4.y), pack2(b5.x, b5.y),
                                                pack2(b6.x, b6.y), 0u);
                *(uint4*)(dr + 76) = make_uint4(0u, 0u, 0u, 0u);
            }
        }
        __syncthreads();

        f32x4 acc[4][4] = {};
        #pragma unroll
        for (int kc = 0; kc < KC1; ++kc) {
            const int kHalf = kc * 16 + q * 4;
            bf16x8 a[4], b[4];
            #pragma unroll
            for (int i = 0; i < 4; ++i)
                a[i] = *(const bf16x8*)(&As[(rowBase + 16 * i + ln) * KPU1 + kHalf]);
            #pragma unroll
            for (int j = 0; j < 4; ++j)
                b[j] = *(const bf16x8*)(Wp + (64 * (wv & 1) + 16 * j + ln) * KPU1 + kHalf);
            #pragma unroll
            for (int i = 0; i < 4; ++i)
                #pragma unroll
                for (int j = 0; j < 4; ++j)
                    acc[i][j] = __builtin_amdgcn_mfma_f32_16x16x32_bf16(a[i], b[j], acc[i][j], 0, 0, 0);
        }
        __syncthreads();

        #pragma unroll
        for (int i = 0; i < 4; ++i) {
            #pragma unroll
            for (int r = 0; r < 4; ++r) {
                int f = fidx[e0 + rowBase + 16 * i + q * 4 + r];
                u32* orow = hout + (size_t)f * 64;
                orow[cbU + ln]      = pack2(relu(acc[i][0][r]), relu(acc[i][1][r]));
                orow[cbU + 16 + ln] = pack2(relu(acc[i][2][r]), relu(acc[i][3][r]));
            }
        }
    }
}

// ---------------- k_msg: 64-pair tiles (128 edges, pair-closed rev) ----------------
__global__ __launch_bounds__(256, 4)
void k_msg(const int* __restrict__ src, const int* __restrict__ rev,
           const u32* __restrict__ Wp, const u32* __restrict__ tmp,
           u32* __restrict__ h)
{
    __shared__ u32 As[128 * KPU2];   // 34816 B -> 4 blocks/CU
    const int tid = threadIdx.x;
    const int lane = tid & 63;
    const int wv = tid >> 6;
    const int ln = lane & 15;
    const int q  = lane >> 4;
    const int rowBase = 64 * (wv >> 1);
    const int cbU = 32 * (wv & 1);
    const int ntiles = NP / 64;

    const int srow = tid >> 1;
    const int half = tid & 1;

    for (int tile = blockIdx.x; tile < ntiles; tile += gridDim.x) {
        const int p0 = tile * 64;
        {
            int e = (srow < 64) ? (p0 + srow) : (NP + p0 + (srow - 64));
            const u32* tp = tmp + (size_t)src[e] * 64 + half * 32;
            const u32* hp = h + (size_t)rev[e] * 64 + half * 32;
            u32* dr = As + srow * KPU2 + half * 32;
            #pragma unroll
            for (int j = 0; j < 8; ++j) {
                uint4 tv = ((const uint4*)tp)[j];
                uint4 hv = ((const uint4*)hp)[j];
                uint4 o;
                o.x = sub2(tv.x, hv.x); o.y = sub2(tv.y, hv.y);
                o.z = sub2(tv.z, hv.z); o.w = sub2(tv.w, hv.w);
                ((uint4*)dr)[j] = o;
            }
        }
        __syncthreads();

        f32x4 acc[4][4] = {};
        #pragma unroll
        for (int kc = 0; kc < KC2; ++kc) {
            const int kHalf = kc * 16 + q * 4;
            bf16x8 a[4], b[4];
            #pragma unroll
            for (int i = 0; i < 4; ++i)
                a[i] = *(const bf16x8*)(&As[(rowBase + 16 * i + ln) * KPU2 + kHalf]);
            #pragma unroll
            for (int j = 0; j < 4; ++j)
                b[j] = *(const bf16x8*)(Wp + (64 * (wv & 1) + 16 * j + ln) * KPU2 + kHalf);
            #pragma unroll
            for (int i = 0; i < 4; ++i)
                #pragma unroll
                for (int j = 0; j < 4; ++j)
                    acc[i][j] = __builtin_amdgcn_mfma_f32_16x16x32_bf16(a[i], b[j], acc[i][j], 0, 0, 0);
        }
        __syncthreads();

        #pragma unroll
        for (int i = 0; i < 4; ++i) {
            #pragma unroll
            for (int r = 0; r < 4; ++r) {
                int rloc = rowBase + 16 * i + q * 4 + r;
                int e = (rloc < 64) ? (p0 + rloc) : (NP + p0 + (rloc - 64));
                u32* orow = h + (size_t)e * 64;
                orow[cbU + ln]      = pack2(relu(acc[i][0][r]), relu(acc[i][1][r]));
                orow[cbU + 16 + ln] = pack2(relu(acc[i][2][r]), relu(acc[i][3][r]));
            }
        }
    }
}

// ---------------- k_out: 64-node tiles, 4 waves (32x64 each) ----------------
__global__ __launch_bounds__(256, 4)
void k_out(const u32* __restrict__ atomBf, const u32* __restrict__ Wp,
           const u32* __restrict__ tmp, float* __restrict__ out)
{
    __shared__ u32 As[64 * KPU3];   // 37888 B -> 4 blocks/CU
    const int tid = threadIdx.x;
    const int lane = tid & 63;
    const int wv = tid >> 6;
    const int ln = lane & 15;
    const int q  = lane >> 4;
    const int rowBase = 32 * (wv >> 1);
    const int colBase = 64 * (wv & 1);
    const int ntiles = (NN + 63) / 64;

    const int srow = tid >> 2;
    const int qt = tid & 3;
    const uint4 z4 = make_uint4(0u, 0u, 0u, 0u);

    for (int tile = blockIdx.x; tile < ntiles; tile += gridDim.x) {
        const int n0 = tile * 64;
        {
            int n = n0 + srow;
            bool ok = n < NN;
            const u32* ap = atomBf + (size_t)n * ATU;
            const u32* tp = tmp + (size_t)n * 64;
            u32* dr = As + srow * KPU3;
            if (qt == 0) {
                #pragma unroll
                for (int j = 0; j < 9; ++j)
                    *(uint4*)(dr + 4 * j) = ok ? *(const uint4*)(ap + 4 * j) : z4;
            } else if (qt == 1) {
                #pragma unroll
                for (int j = 9; j < 17; ++j)
                    *(uint4*)(dr + 4 * j) = ok ? *(const uint4*)(ap + 4 * j) : z4;
            } else if (qt == 2) {
                #pragma unroll
                for (int j = 0; j < 8; ++j)
                    *(uint4*)(dr + 68 + 4 * j) = ok ? *(const uint4*)(tp + 4 * j) : z4;
                *(uint4*)(dr + 132) = z4;
            } else {
                #pragma unroll
                for (int j = 8; j < 16; ++j)
                    *(uint4*)(dr + 68 + 4 * j) = ok ? *(const uint4*)(tp + 4 * j) : z4;
                *(uint4*)(dr + 136) = z4;
                *(uint4*)(dr + 140) = z4;
            }
        }
        __syncthreads();

        f32x4 acc[2][4] = {};
        #pragma unroll
        for (int kc = 0; kc < KC3; ++kc) {
            const int kHalf = kc * 16 + q * 4;
            bf16x8 a[2], b[4];
            #pragma unroll
            for (int i = 0; i < 2; ++i)
                a[i] = *(const bf16x8*)(&As[(rowBase + 16 * i + ln) * KPU3 + kHalf]);
            #pragma unroll
            for (int j = 0; j < 4; ++j)
                b[j] = *(const bf16x8*)(Wp + (colBase + 16 * j + ln) * KPU3 + kHalf);
            #pragma unroll
            for (int i = 0; i < 2; ++i)
                #pragma unroll
                for (int j = 0; j < 4; ++j)
                    acc[i][j] = __builtin_amdgcn_mfma_f32_16x16x32_bf16(a[i], b[j], acc[i][j], 0, 0, 0);
        }
        __syncthreads();

        #pragma unroll
        for (int i = 0; i < 2; ++i) {
            #pragma unroll
            for (int r = 0; r < 4; ++r) {
                int n = n0 + rowBase + 16 * i + q * 4 + r;
                if (n < NN) {
                    float2* orow = (float2*)(out + (size_t)n * HID);
                    float2 v01, v23;
                    v01.x = relu(acc[i][0][r]); v01.y = relu(acc[i][1][r]);
                    v23.x = relu(acc[i][2][r]); v23.y = relu(acc[i][3][r]);
                    orow[(colBase >> 1) + ln]      = v01;
                    orow[(colBase >> 1) + 16 + ln] = v23;
                }
            }
        }
    }
}

// ---------------- launch ----------------

extern "C" void kernel_launch(void* const* d_in, const int* in_sizes, int n_in,
                              void* d_out, int out_size, void* d_ws, size_t ws_size,
                              hipStream_t stream) {
    const float* atom = (const float*)d_in[0];   // [50000][133]
    const float* bond = (const float*)d_in[1];   // [800000][14]
    const float* Wi   = (const float*)d_in[2];   // [128][147]
    const float* Wh   = (const float*)d_in[3];   // [128][128]
    const float* Wo   = (const float*)d_in[4];   // [128][261]
    const int*   src  = (const int*)d_in[5];
    const int*   dst  = (const int*)d_in[6];
    const int*   rev  = (const int*)d_in[7];
    float* out = (float*)d_out;

    char* ws = (char*)d_ws;
    size_t off = 0;
    auto take = [&](size_t bytes) { char* p = ws + off; off = (off + bytes + 255) & ~(size_t)255; return p; };
    u32* hbuf   = (u32*)take((size_t)NE * 64 * 4);     // 204.8 MB  bf16 h[E][128]
    u32* tmp    = (u32*)take((size_t)NN * 64 * 4);     // 12.8 MB   bf16 tmp[N][128]
    u32* atomBf = (u32*)take((size_t)NN * ATU * 4);    // 13.6 MB
    int* eidx   = (int*)take((size_t)NE * 4);          // 3.2 MB
    int* fidx   = (int*)take((size_t)NE * 4);          // 3.2 MB
    int* sidx   = (int*)take((size_t)NE * 4);          // 3.2 MB
    int* cnt    = (int*)take((size_t)NN * 4);
    int* lexc   = (int*)take((size_t)NN * 4);
    int* rowptr = (int*)take((size_t)(NN + 1) * 4);
    int* cursor = (int*)take((size_t)NN * 4);
    int* chunkSum = (int*)take(256 * 4);
    int* chunkOff = (int*)take(256 * 4);
    u32* WiP = (u32*)take(128 * KPU1 * 4);
    u32* WhP = (u32*)take(128 * KPU2 * 4);
    u32* WoP = (u32*)take(128 * KPU3 * 4);
    // total ~242 MB

    cvt_atom<<<2048, 256, 0, stream>>>(atom, atomBf);
    cvt_w<<<48, 256, 0, stream>>>(Wi, WiP, 147, KPU1, 133, 136, 14);
    cvt_w<<<48, 256, 0, stream>>>(Wh, WhP, 128, KPU2, 128, 1 << 20, 0);
    cvt_w<<<80, 256, 0, stream>>>(Wo, WoP, 261, KPU3, 133, 136, 128);

    hipMemsetAsync(cnt, 0, (size_t)NN * 4, stream);
    hist<<<1024, 256, 0, stream>>>(dst, cnt);
    scan1<<<NCH, 256, 0, stream>>>(cnt, lexc, chunkSum);
    scan2<<<1, 256, 0, stream>>>(chunkSum, chunkOff);
    scan3<<<NCH, 256, 0, stream>>>(lexc, chunkOff, rowptr, cursor);
    scatter<<<1024, 256, 0, stream>>>(dst, rev, cursor, eidx, fidx, sidx);

    k_init<<<768, 256, 0, stream>>>(atomBf, bond, fidx, sidx, WiP, hbuf);
    segsum<<<2048, 256, 0, stream>>>(rowptr, eidx, hbuf, tmp);
    k_msg<<<1024, 256, 0, stream>>>(src, rev, WhP, tmp, hbuf);
    segsum<<<2048, 256, 0, stream>>>(rowptr, eidx, hbuf, tmp);
    k_msg<<<1024, 256, 0, stream>>>(src, rev, WhP, tmp, hbuf);
    segsum<<<2048, 256, 0, stream>>>(rowptr, eidx, hbuf, tmp);
    k_out<<<782, 256, 0, stream>>>(atomBf, WoP, tmp, out);
}